// Round 1
// baseline (3174.024 us; speedup 1.0000x reference)
//
#include <hip/hip_runtime.h>
#include <math.h>

// Problem constants (from reference setup_inputs)
#define NROWS 16384
#define KD 2048      // FEAT (encoder K)
#define ND 2048      // FEAT (encoder N)
#define NCLS 20
#define SMARG 0.31f

// Tiling
#define TM 64        // rows per block
#define BN 128       // h-column chunk per iteration
#define BK 32        // K stage
#define NT 256       // threads per block

// LDS strides (floats). AS/BS strides chosen: %4==0 (16B-aligned float4 rows)
// and not %32==0 at the read-access granularity (conflict-free wave patterns).
#define AS_STR 68    // As[k][row] transposed, [BK][TM+pad]
#define BS_STR 132   // Bs[k][col], [BK][BN+pad]
#define HS_STR 129   // Hs[row][col] (scalar writes, stride odd => 2-way-free reads)
#define BS_OFF (BK * AS_STR)              // 2176 floats
#define HS_OFF (BS_OFF + BK * BS_STR)     // 6400 floats
#define SMEM_FLOATS (HS_OFF + TM * HS_STR) // 14656 floats = 58,624 B (< 64 KiB)

__global__ __launch_bounds__(NT)
void fused_hybrid_fp32(const float* __restrict__ X,
                       const float* __restrict__ We,
                       const float* __restrict__ be,
                       const float* __restrict__ Wc,
                       const float* __restrict__ bc,
                       const float* __restrict__ Wf,
                       const float* __restrict__ bf,
                       float* __restrict__ out)
{
    __shared__ __align__(16) float smem[SMEM_FLOATS];
    float* As = smem;                 // [BK][AS_STR]  (A transposed: As[k][row])
    float* Bs = smem + BS_OFF;        // [BK][BS_STR]
    float* Hs = smem + HS_OFF;        // [TM][HS_STR]
    // Aliases over the As/Bs region (dead during stage-2 / epilogue):
    float* Wcs = smem;                // [BN][21] = 2688 floats
    float* Wfs = smem + 2688;         // [BN][21] -> ends 5376 < HS_OFF
    float* Lc  = smem;                // [TM][21] = 1344 floats (epilogue only)
    float* Lf  = smem + 1344;         // ends 2688

    const int tid  = threadIdx.x;
    const int row0 = blockIdx.x * TM;

    // main-GEMM micro-tile map: 16x16 thread grid, 4 rows x 8 cols each
    const int ty = tid >> 4;          // 0..15 -> rows 4*ty..4*ty+3
    const int tx = tid & 15;          // 0..15 -> cols 8*tx..8*tx+7

    // stage-2 map: (row, col-group) = (tid&63, tid>>6); 4 groups x 5 cols
    const int s2row = tid & 63;
    const int s2g   = tid >> 6;       // 0..3 -> cols 5*s2g .. 5*s2g+4

    float aC[5], aF[5];
    #pragma unroll
    for (int j = 0; j < 5; ++j) {
        aC[j] = bc[5*s2g + j];
        aF[j] = bf[5*s2g + j];
    }

    for (int n0 = 0; n0 < ND; n0 += BN) {
        float acc[4][8];
        #pragma unroll
        for (int i = 0; i < 4; ++i)
            #pragma unroll
            for (int j = 0; j < 8; ++j) acc[i][j] = 0.f;

        float4 aR[2], bR[4];
        // ---- prologue: load stage 0 (k0 = 0) into registers ----
        #pragma unroll
        for (int it = 0; it < 2; ++it) {
            int fid = tid + NT*it;
            int arow = fid >> 3, akg = fid & 7;          // 64 rows x 8 k-quads
            aR[it] = *(const float4*)(X + (size_t)(row0 + arow)*KD + 4*akg);
        }
        #pragma unroll
        for (int it = 0; it < 4; ++it) {
            int fid = tid + NT*it;
            int bkk = fid >> 5, bc4 = fid & 31;          // 32 k-rows x 32 col-quads
            bR[it] = *(const float4*)(We + (size_t)bkk*ND + n0 + 4*bc4);
        }
        __syncthreads();   // prior chunk's stage-2 reads of Wcs/As/Bs are done
        #pragma unroll
        for (int it = 0; it < 2; ++it) {
            int fid = tid + NT*it;
            int arow = fid >> 3, akg = fid & 7;
            As[(4*akg+0)*AS_STR + arow] = aR[it].x;
            As[(4*akg+1)*AS_STR + arow] = aR[it].y;
            As[(4*akg+2)*AS_STR + arow] = aR[it].z;
            As[(4*akg+3)*AS_STR + arow] = aR[it].w;
        }
        #pragma unroll
        for (int it = 0; it < 4; ++it) {
            int fid = tid + NT*it;
            int bkk = fid >> 5, bc4 = fid & 31;
            *(float4*)(Bs + bkk*BS_STR + 4*bc4) = bR[it];
        }
        __syncthreads();

        // ---- K loop: software-pipelined (register prefetch of next stage) ----
        for (int k0 = 0; k0 < KD; k0 += BK) {
            const bool nxt = (k0 + BK) < KD;
            if (nxt) {
                #pragma unroll
                for (int it = 0; it < 2; ++it) {
                    int fid = tid + NT*it;
                    int arow = fid >> 3, akg = fid & 7;
                    aR[it] = *(const float4*)(X + (size_t)(row0 + arow)*KD + (k0 + BK) + 4*akg);
                }
                #pragma unroll
                for (int it = 0; it < 4; ++it) {
                    int fid = tid + NT*it;
                    int bkk = fid >> 5, bc4 = fid & 31;
                    bR[it] = *(const float4*)(We + (size_t)(k0 + BK + bkk)*ND + n0 + 4*bc4);
                }
            }
            #pragma unroll
            for (int kk = 0; kk < BK; ++kk) {
                float4 av  = *(const float4*)(As + kk*AS_STR + 4*ty);   // broadcast
                float4 bv0 = *(const float4*)(Bs + kk*BS_STR + 8*tx);   // contiguous
                float4 bv1 = *(const float4*)(Bs + kk*BS_STR + 8*tx + 4);
                float a_[4] = {av.x, av.y, av.z, av.w};
                float b_[8] = {bv0.x, bv0.y, bv0.z, bv0.w, bv1.x, bv1.y, bv1.z, bv1.w};
                #pragma unroll
                for (int i = 0; i < 4; ++i)
                    #pragma unroll
                    for (int j = 0; j < 8; ++j)
                        acc[i][j] = fmaf(a_[i], b_[j], acc[i][j]);
            }
            __syncthreads();   // all reads of As/Bs done
            if (nxt) {
                #pragma unroll
                for (int it = 0; it < 2; ++it) {
                    int fid = tid + NT*it;
                    int arow = fid >> 3, akg = fid & 7;
                    As[(4*akg+0)*AS_STR + arow] = aR[it].x;
                    As[(4*akg+1)*AS_STR + arow] = aR[it].y;
                    As[(4*akg+2)*AS_STR + arow] = aR[it].z;
                    As[(4*akg+3)*AS_STR + arow] = aR[it].w;
                }
                #pragma unroll
                for (int it = 0; it < 4; ++it) {
                    int fid = tid + NT*it;
                    int bkk = fid >> 5, bc4 = fid & 31;
                    *(float4*)(Bs + bkk*BS_STR + 4*bc4) = bR[it];
                }
                __syncthreads();
            }
        }

        // ---- write H chunk (+ b_enc) to LDS; stage W_cls/W_fl chunk over As/Bs ----
        const float4 be0 = *(const float4*)(be + n0 + 8*tx);
        const float4 be1 = *(const float4*)(be + n0 + 8*tx + 4);
        #pragma unroll
        for (int i = 0; i < 4; ++i) {
            float* hp = Hs + (4*ty + i)*HS_STR + 8*tx;
            hp[0] = acc[i][0] + be0.x;  hp[1] = acc[i][1] + be0.y;
            hp[2] = acc[i][2] + be0.z;  hp[3] = acc[i][3] + be0.w;
            hp[4] = acc[i][4] + be1.x;  hp[5] = acc[i][5] + be1.y;
            hp[6] = acc[i][6] + be1.z;  hp[7] = acc[i][7] + be1.w;
        }
        #pragma unroll
        for (int m = 0; m < 10; ++m) {
            int idx = tid + NT*m;                 // 0..2559 covers [BN][NCLS]
            int kx = idx / 20, cx = idx % 20;
            Wcs[kx*21 + cx] = Wc[(size_t)(n0 + kx)*NCLS + cx];
            Wfs[kx*21 + cx] = Wf[(size_t)(n0 + kx)*NCLS + cx];
        }
        __syncthreads();

        // ---- stage 2: logits += H_chunk @ W_chunk (both heads) ----
        {
            const float* hp = Hs + s2row*HS_STR;
            #pragma unroll 2
            for (int k = 0; k < BN; ++k) {
                float hv = hp[k];                          // 2-way free (stride 129)
                const float* wc = Wcs + k*21 + 5*s2g;      // wave-uniform -> broadcast
                const float* wf = Wfs + k*21 + 5*s2g;
                #pragma unroll
                for (int j = 0; j < 5; ++j) {
                    aC[j] = fmaf(hv, wc[j], aC[j]);
                    aF[j] = fmaf(hv, wf[j], aF[j]);
                }
            }
        }
        // next chunk's first __syncthreads() protects As/Bs/Wcs overwrite
    }

    // ---- epilogue: dual softmax + confidence threshold ----
    __syncthreads();                   // stage-2 reads done before Lc/Lf overwrite
    #pragma unroll
    for (int j = 0; j < 5; ++j) {
        Lc[s2row*21 + 5*s2g + j] = aC[j];
        Lf[s2row*21 + 5*s2g + j] = aF[j];
    }
    __syncthreads();
    if (tid < TM) {
        const float* lcp = Lc + tid*21;
        const float* lfp = Lf + tid*21;
        float mC = lcp[0], mF = lfp[0], mnF = lfp[0];
        #pragma unroll
        for (int c = 1; c < NCLS; ++c) {
            mC = fmaxf(mC, lcp[c]);
            float v = lfp[c];
            mF = fmaxf(mF, v);
            mnF = fminf(mnF, v);
        }
        float sC = 0.f, sF = 0.f;
        #pragma unroll
        for (int c = 0; c < NCLS; ++c) {
            sC += expf(lcp[c] - mC);
            sF += expf(lfp[c] - mF);
        }
        float pred = 1.f / sC;                    // max softmax == exp(0)/sum exactly
        float tau  = expf(mnF - mF) / sF;         // min softmax of flow head
        float scale = (pred >= tau + SMARG) ? pred : 0.f;
        float* op = out + (size_t)(row0 + tid)*NCLS;
        #pragma unroll
        for (int c = 0; c < NCLS; ++c)
            op[c] = expf(lcp[c] - mC) * scale;
    }
}

extern "C" void kernel_launch(void* const* d_in, const int* in_sizes, int n_in,
                              void* d_out, int out_size, void* d_ws, size_t ws_size,
                              hipStream_t stream) {
    const float* X  = (const float*)d_in[0];
    const float* We = (const float*)d_in[1];
    const float* be = (const float*)d_in[2];
    const float* Wc = (const float*)d_in[3];
    const float* bc = (const float*)d_in[4];
    const float* Wf = (const float*)d_in[5];
    const float* bf = (const float*)d_in[6];
    float* out = (float*)d_out;
    (void)d_ws; (void)ws_size; (void)in_sizes; (void)n_in; (void)out_size;

    fused_hybrid_fp32<<<dim3(NROWS / TM), dim3(NT), 0, stream>>>(
        X, We, be, Wc, bc, Wf, bf, out);
}

// Round 2
// 1017.160 us; speedup vs baseline: 3.1205x; 3.1205x over previous
//
#include <hip/hip_runtime.h>
#include <math.h>

// Algebraic collapse: out depends on h = X@We + be only through h@Wc and h@Wf.
//   logits[:, 0:20]  = X @ (We@Wc) + (be@Wc + bc)
//   logits[:, 20:40] = X @ (We@Wf) + (be@Wf + bf)
// => never compute the 2048x2048 encoder GEMM (137 GFLOP -> 2.7 GFLOP).

#define NROWS 16384
#define KD    2048
#define NCLS  20
#define NC2   40
#define SMARG 0.31f
#define NSPLIT 16
#define KSEG  (KD / NSPLIT)     // 128

// ws layout (floats):
#define WEFF_OFF 0              // [2048][40]        = 81920 floats
#define BIAS_OFF 81920          // [40]
#define LOG_OFF  82048          // [16384][40]       = 655360 floats (byte off 328192, 64B aligned)
// total = 737,408 floats = 2,949,632 bytes

// ---------------- K1: fold weights, fold biases, zero logits ----------------
__global__ __launch_bounds__(256)
void k1_fold(const float* __restrict__ We, const float* __restrict__ be,
             const float* __restrict__ Wc, const float* __restrict__ bc,
             const float* __restrict__ Wf, const float* __restrict__ bf,
             float* __restrict__ ws)
{
    const int t = blockIdx.x * 256 + threadIdx.x;   // 0..81919
    // zero the logits accumulator region (8 floats per thread, float4 stores)
    {
        float4 z = make_float4(0.f, 0.f, 0.f, 0.f);
        float4* lp = (float4*)(ws + LOG_OFF + (size_t)t * 8);
        lp[0] = z; lp[1] = z;
    }
    const int k = t / NC2;
    const int c = t % NC2;
    const float* Wp = (c < NCLS) ? Wc : Wf;
    const int cc = (c < NCLS) ? c : (c - NCLS);
    const float* wer = We + (size_t)k * KD;
    float acc = 0.f;
    for (int n = 0; n < KD; n += 4) {
        float4 w4 = *(const float4*)(wer + n);      // wave-shared (broadcast)
        acc = fmaf(w4.x, Wp[(n + 0) * NCLS + cc], acc);
        acc = fmaf(w4.y, Wp[(n + 1) * NCLS + cc], acc);
        acc = fmaf(w4.z, Wp[(n + 2) * NCLS + cc], acc);
        acc = fmaf(w4.w, Wp[(n + 3) * NCLS + cc], acc);
    }
    ws[WEFF_OFF + t] = acc;                         // Weff[k][c], row-major [2048][40]
    if (t < NC2) {                                  // fold biases: be@Wcat + [bc|bf]
        float b = (c < NCLS) ? bc[cc] : bf[cc];
        float acc2 = 0.f;
        for (int n = 0; n < KD; ++n)
            acc2 = fmaf(be[n], Wp[n * NCLS + cc], acc2);
        ws[BIAS_OFF + t] = acc2 + b;
    }
}

// ---------------- K2: skinny GEMM X[16384,2048] @ Weff[2048,40], split-K ----
// Row-per-lane: each lane owns one output row => Weff addresses are
// wave-uniform (scalar-cache loads), no LDS, no shuffles. 16-way split-K
// (4096 waves = 16 waves/CU) with device-scope float atomics into logits.
__global__ __launch_bounds__(256)
void k2_gemm(const float* __restrict__ X, const float* __restrict__ weff,
             float* __restrict__ logits)
{
    const int b     = blockIdx.x;            // 0..1023
    const int rowg  = b & 255;               // 256 row groups of 64
    const int sgrp  = b >> 8;                // 0..3
    const int wv    = threadIdx.x >> 6;      // 0..3
    const int lane  = threadIdx.x & 63;
    const int split = sgrp * 4 + wv;         // 0..15
    const int row   = rowg * 64 + lane;

    const float* xr = X + (size_t)row * KD + split * KSEG;
    const float* wr = weff + (size_t)split * KSEG * NC2;

    float acc[NC2];
    #pragma unroll
    for (int c = 0; c < NC2; ++c) acc[c] = 0.f;

    for (int k0 = 0; k0 < KSEG; k0 += 4) {
        float4 x4 = *(const float4*)(xr + k0);
        float xs[4] = {x4.x, x4.y, x4.z, x4.w};
        #pragma unroll
        for (int j = 0; j < 4; ++j) {
            const float4* w4 = (const float4*)(wr + (k0 + j) * NC2);  // wave-uniform
            #pragma unroll
            for (int q = 0; q < 10; ++q) {
                float4 wv4 = w4[q];
                acc[4 * q + 0] = fmaf(xs[j], wv4.x, acc[4 * q + 0]);
                acc[4 * q + 1] = fmaf(xs[j], wv4.y, acc[4 * q + 1]);
                acc[4 * q + 2] = fmaf(xs[j], wv4.z, acc[4 * q + 2]);
                acc[4 * q + 3] = fmaf(xs[j], wv4.w, acc[4 * q + 3]);
            }
        }
    }

    float* lr = logits + (size_t)row * NC2;
    #pragma unroll
    for (int c = 0; c < NC2; ++c)
        atomicAdd(lr + c, acc[c]);           // device-scope by default on CDNA
}

// ---------------- K3: bias + dual softmax + confidence threshold -----------
__global__ __launch_bounds__(256)
void k3_epilogue(const float* __restrict__ logits, const float* __restrict__ bias2,
                 float* __restrict__ out)
{
    const int row = blockIdx.x * 256 + threadIdx.x;   // 0..16383
    const float* lr = logits + (size_t)row * NC2;
    float l[NC2];
    #pragma unroll
    for (int q = 0; q < 10; ++q) {
        float4 v  = ((const float4*)lr)[q];
        float4 bb = ((const float4*)bias2)[q];        // wave-uniform
        l[4 * q + 0] = v.x + bb.x;
        l[4 * q + 1] = v.y + bb.y;
        l[4 * q + 2] = v.z + bb.z;
        l[4 * q + 3] = v.w + bb.w;
    }
    float mC = l[0];
    #pragma unroll
    for (int c = 1; c < NCLS; ++c) mC = fmaxf(mC, l[c]);
    float sC = 0.f;
    #pragma unroll
    for (int c = 0; c < NCLS; ++c) sC += expf(l[c] - mC);

    float mF = l[NCLS], mnF = l[NCLS];
    #pragma unroll
    for (int c = NCLS + 1; c < NC2; ++c) {
        float v = l[c];
        mF = fmaxf(mF, v);
        mnF = fminf(mnF, v);
    }
    float sF = 0.f;
    #pragma unroll
    for (int c = NCLS; c < NC2; ++c) sF += expf(l[c] - mF);

    float pred = 1.f / sC;                  // max softmax = exp(0)/sum
    float tau  = expf(mnF - mF) / sF;       // min softmax of flow head
    float scale = (pred >= tau + SMARG) ? (1.f / sC) : 0.f;

    float* op = out + (size_t)row * NCLS;
    #pragma unroll
    for (int c = 0; c < NCLS; ++c)
        op[c] = expf(l[c] - mC) * scale;
}

extern "C" void kernel_launch(void* const* d_in, const int* in_sizes, int n_in,
                              void* d_out, int out_size, void* d_ws, size_t ws_size,
                              hipStream_t stream) {
    const float* X  = (const float*)d_in[0];
    const float* We = (const float*)d_in[1];
    const float* be = (const float*)d_in[2];
    const float* Wc = (const float*)d_in[3];
    const float* bc = (const float*)d_in[4];
    const float* Wf = (const float*)d_in[5];
    const float* bf = (const float*)d_in[6];
    float* out = (float*)d_out;
    float* ws  = (float*)d_ws;
    (void)in_sizes; (void)n_in; (void)out_size; (void)ws_size;

    // K1: fold We@[Wc|Wf] -> Weff[2048][40], fold biases, zero logits region
    k1_fold<<<dim3(320), dim3(256), 0, stream>>>(We, be, Wc, bc, Wf, bf, ws);
    // K2: logits = X @ Weff (split-K 16, atomic accumulate)
    k2_gemm<<<dim3(1024), dim3(256), 0, stream>>>(X, ws + WEFF_OFF, ws + LOG_OFF);
    // K3: + bias2, dual softmax, threshold, write out
    k3_epilogue<<<dim3(NROWS / 256), dim3(256), 0, stream>>>(ws + LOG_OFF, ws + BIAS_OFF, out);
}

// Round 3
// 243.014 us; speedup vs baseline: 13.0611x; 4.1856x over previous
//
#include <hip/hip_runtime.h>
#include <math.h>

// Algebraic collapse: out depends on h = X@We + be only through h@Wc and h@Wf.
//   logits[:, 0:20]  = X @ (We@Wc) + (be@Wc + bc)
//   logits[:, 20:40] = X @ (We@Wf) + (be@Wf + bf)
// K0: pack Wcat=[Wc|Wf], zero Weff, fold bias2 = be@Wcat + [bc|bf]
// K1: Weff = We @ Wcat        (skinny GEMM template, atomic split-K)
// K2: out  = epilogue(X @ Weff + bias2)   (fused softmax+threshold)

#define KD    2048
#define NROWS 16384
#define NCLS  20
#define NC2   40
#define SMARG 0.31f

// ws layout (floats): total 163,880 floats = 656 KB
#define WCAT_OFF 0
#define WEFF_OFF 81920
#define BIAS_OFF 163840

#define XS_STR  65            // Xs[k][row], 65 mod 32 = 1 -> conflict-free
#define XS_BUF  (64 * XS_STR) // 4160 floats per buffer
#define HACC_STR 41           // Hacc[ks][row][c], 41 odd -> conflict-free
#define HACC_WS  (64 * HACC_STR)
#define SMEM_FLOATS (8 * HACC_WS)   // 20992 > 2*XS_BUF(8320); union of Xs-dbuf / Hacc

// ---------------- K0: pack Wcat, zero Weff, fold bias2 ----------------------
__global__ __launch_bounds__(256)
void k0_prep(const float* __restrict__ Wc, const float* __restrict__ bc,
             const float* __restrict__ Wf, const float* __restrict__ bf,
             const float* __restrict__ be, float* __restrict__ ws)
{
    const int b = blockIdx.x;
    const int t = threadIdx.x;
    if (b < 320) {
        const int idx = b * 256 + t;                 // 0..81919
        const int n = idx / NC2, c = idx % NC2;
        ws[WCAT_OFF + idx] = (c < NCLS) ? Wc[n * NCLS + c] : Wf[n * NCLS + (c - NCLS)];
        ws[WEFF_OFF + idx] = 0.f;                    // ws re-poisoned each call
    } else {
        const int col = b - 320;                     // 0..39
        const float* Wp = (col < NCLS) ? Wc : Wf;
        const int cc = (col < NCLS) ? col : col - NCLS;
        float p = 0.f;
        for (int n = t; n < KD; n += 256)
            p = fmaf(be[n], Wp[n * NCLS + cc], p);
        __shared__ float red[256];
        red[t] = p;
        __syncthreads();
        for (int s = 128; s > 0; s >>= 1) {
            if (t < s) red[t] += red[t + s];
            __syncthreads();
        }
        if (t == 0)
            ws[BIAS_OFF + col] = red[0] + ((col < NCLS) ? bc[cc] : bf[cc]);
    }
}

// ---------------- skinny GEMM core: C[M,40] (+=) A[M,2048] @ Bw[2048,40] ----
// Block: 1024 thr = 16 waves = 2 col-groups x 8 in-chunk K-splits over ONE
// shared 64-row x 64-k LDS tile (double-buffered). Bw is read via wave-uniform
// addresses (readfirstlane-forced) -> scalar s_loads, zero LDS/VMEM-per-lane
// cost. X: coalesced float4 global loads (lanes span k), transposed stride-65
// LDS store (conflict-free both ways). In-block LDS reduce over the 8 K-splits.
template<int NCHUNKS, bool FUSED>
__global__ __launch_bounds__(1024)
void skinny_gemm(const float* __restrict__ A,
                 const float* __restrict__ Bw,
                 float* __restrict__ Cacc,           // !FUSED: atomic target
                 const float* __restrict__ bias2,    // FUSED
                 float* __restrict__ outp)           // FUSED
{
    __shared__ float smem[SMEM_FLOATS];
    const int tid  = threadIdx.x;
    const int lane = tid & 63;
    const int wu   = __builtin_amdgcn_readfirstlane(tid >> 6);  // wave id 0..15
    const int cgu  = wu & 1;           // col-group: 20 cols
    const int ksu  = wu >> 1;          // in-chunk k-split 0..7
    const int ksub = ksu * 8;

    int m0, kbase;
    if (FUSED) { m0 = blockIdx.x * 64;        kbase = 0; }
    else       { m0 = (blockIdx.x >> 2) * 64; kbase = (blockIdx.x & 3) * (NCHUNKS * 64); }

    const int lrow = tid >> 4;         // 0..63 (4 rows per wave -> 256B segments)
    const int lkq  = tid & 15;         // 16 float4 per row = 64 k
    const float* aptr = A + (size_t)(m0 + lrow) * KD + kbase + 4 * lkq;

    float acc[20];
    #pragma unroll
    for (int j = 0; j < 20; ++j) acc[j] = 0.f;

    // prologue: stage chunk 0 into buf 0
    float4 v = *(const float4*)(aptr);
    {
        float* xb = smem;
        xb[(4 * lkq + 0) * XS_STR + lrow] = v.x;
        xb[(4 * lkq + 1) * XS_STR + lrow] = v.y;
        xb[(4 * lkq + 2) * XS_STR + lrow] = v.z;
        xb[(4 * lkq + 3) * XS_STR + lrow] = v.w;
    }
    __syncthreads();

    for (int c = 0; c < NCHUNKS; ++c) {
        const int buf = c & 1;
        if (c + 1 < NCHUNKS)
            v = *(const float4*)(aptr + (c + 1) * 64);   // prefetch next chunk

        const float* xs   = smem + buf * XS_BUF;
        const float* brow = Bw + (size_t)(kbase + c * 64 + ksub) * NC2 + 20 * cgu;
        #pragma unroll 4
        for (int kk = 0; kk < 8; ++kk) {
            float x = xs[(ksub + kk) * XS_STR + lane];    // conflict-free gather
            #pragma unroll
            for (int j = 0; j < 20; ++j)
                acc[j] = fmaf(x, brow[kk * NC2 + j], acc[j]);  // s_load operand
        }

        if (c + 1 < NCHUNKS) {
            float* xb = smem + (buf ^ 1) * XS_BUF;
            xb[(4 * lkq + 0) * XS_STR + lrow] = v.x;
            xb[(4 * lkq + 1) * XS_STR + lrow] = v.y;
            xb[(4 * lkq + 2) * XS_STR + lrow] = v.z;
            xb[(4 * lkq + 3) * XS_STR + lrow] = v.w;
        }
        __syncthreads();
    }

    // in-block reduce over the 8 k-splits: Hacc[ks][row][c]  (aliases Xs, dead now)
    float* H = smem;
    #pragma unroll
    for (int j = 0; j < 20; ++j)
        H[ksu * HACC_WS + lane * HACC_STR + 20 * cgu + j] = acc[j];
    __syncthreads();

    if (FUSED) {
        if (tid < 64) {
            float l[NC2];
            #pragma unroll
            for (int cc = 0; cc < NC2; ++cc) {
                float s = 0.f;
                #pragma unroll
                for (int ks = 0; ks < 8; ++ks)
                    s += H[ks * HACC_WS + tid * HACC_STR + cc];
                l[cc] = s + bias2[cc];
            }
            float mC = l[0];
            #pragma unroll
            for (int cc = 1; cc < NCLS; ++cc) mC = fmaxf(mC, l[cc]);
            float sC = 0.f;
            #pragma unroll
            for (int cc = 0; cc < NCLS; ++cc) sC += expf(l[cc] - mC);
            float mF = l[NCLS], mnF = l[NCLS];
            #pragma unroll
            for (int cc = NCLS + 1; cc < NC2; ++cc) {
                float vv = l[cc];
                mF = fmaxf(mF, vv);
                mnF = fminf(mnF, vv);
            }
            float sF = 0.f;
            #pragma unroll
            for (int cc = NCLS; cc < NC2; ++cc) sF += expf(l[cc] - mF);
            float pred  = 1.f / sC;                  // max softmax == exp(0)/sum
            float tau   = expf(mnF - mF) / sF;       // min softmax of flow head
            float scale = (pred >= tau + SMARG) ? pred : 0.f;
            float* op = outp + (size_t)(m0 + tid) * NCLS;
            #pragma unroll
            for (int cc = 0; cc < NCLS; ++cc)
                op[cc] = expf(l[cc] - mC) * scale;
        }
    } else {
        for (int idx = tid; idx < 64 * NC2; idx += 1024) {
            int row = idx / NC2, cc = idx % NC2;
            float s = 0.f;
            #pragma unroll
            for (int ks = 0; ks < 8; ++ks)
                s += H[ks * HACC_WS + row * HACC_STR + cc];
            atomicAdd(Cacc + (size_t)(m0 + row) * NC2 + cc, s);
        }
    }
}

extern "C" void kernel_launch(void* const* d_in, const int* in_sizes, int n_in,
                              void* d_out, int out_size, void* d_ws, size_t ws_size,
                              hipStream_t stream) {
    const float* X  = (const float*)d_in[0];
    const float* We = (const float*)d_in[1];
    const float* be = (const float*)d_in[2];
    const float* Wc = (const float*)d_in[3];
    const float* bc = (const float*)d_in[4];
    const float* Wf = (const float*)d_in[5];
    const float* bf = (const float*)d_in[6];
    float* out = (float*)d_out;
    float* ws  = (float*)d_ws;
    (void)in_sizes; (void)n_in; (void)out_size; (void)ws_size;

    // K0: pack Wcat, zero Weff, fold bias2
    k0_prep<<<dim3(360), dim3(256), 0, stream>>>(Wc, bc, Wf, bf, be, ws);
    // K1: Weff = We @ Wcat   (M=2048: 32 row-groups x 4 block-K-splits, atomic)
    skinny_gemm<8, false><<<dim3(128), dim3(1024), 0, stream>>>(
        We, ws + WCAT_OFF, ws + WEFF_OFF, nullptr, nullptr);
    // K2: out = softmax-threshold(X @ Weff + bias2)   (M=16384: 256 blocks)
    skinny_gemm<32, true><<<dim3(256), dim3(1024), 0, stream>>>(
        X, ws + WEFF_OFF, nullptr, ws + BIAS_OFF, out);
}